// Round 19
// baseline (56.950 us; speedup 1.0000x reference)
//
#include <hip/hip_runtime.h>

#define TT 768
#define KD 512
#define NC 1024
#define RLN2_2 2.8853900817779268f   // 2/ln(2)

typedef short short8 __attribute__((ext_vector_type(8)));
typedef float f32x4  __attribute__((ext_vector_type(4)));
typedef float f32x2  __attribute__((ext_vector_type(2)));

__device__ __forceinline__ float fast_exp2(float x) {
#if __has_builtin(__builtin_amdgcn_exp2f)
    return __builtin_amdgcn_exp2f(x);
#else
    return exp2f(x);
#endif
}
__device__ __forceinline__ float fast_rcp(float x) {
#if __has_builtin(__builtin_amdgcn_rcpf)
    return __builtin_amdgcn_rcpf(x);
#else
    return 1.0f / x;
#endif
}
__device__ __forceinline__ float fast_tanh(float x) {
    float e = fast_exp2(x * RLN2_2);
    return fmaf(-2.0f, fast_rcp(e + 1.0f), 1.0f);
}
__device__ __forceinline__ ushort f2bf(float f) {   // RNE f32->bf16
    uint u = __float_as_uint(f);
    u += 0x7fff + ((u >> 16) & 1);
    return (ushort)(u >> 16);
}

// ---------------------------------------------------------------------------
// GEMM1 (fused prep): act = tanh( x @ (foh|fom) + catBias ), bf16 out.
// [FROZEN = r18]
// ---------------------------------------------------------------------------
__global__ __launch_bounds__(128) void k_gemm1(
    const float* __restrict__ x, const float* __restrict__ foh,
    const float* __restrict__ fom, const float* __restrict__ catBias,
    ushort* __restrict__ act)
{
    __shared__ float ps[64][20];
    __shared__ float bt[2][32][33];

    const int t = threadIdx.x;
    const int kv = t >> 6, lane = t & 63;
    const int n0 = blockIdx.x * 32;
    const int m0 = blockIdx.y * 32;
    const float* B = (n0 < 512) ? foh : fom;
    const int nc0  = (n0 < 512) ? n0 : n0 - 512;
    const int lrow = lane & 15, lk = (lane >> 4) * 8;
    const int kbase = kv * 256;

    const int skr = lane >> 1;           // k-row 0..31
    const int snc = (lane & 1) * 16;     // col 0 or 16

    const float* px0 = &x[(m0 + lrow) * KD + kbase + lk];
    const float* px1 = px0 + 16 * KD;

    f32x4 acc[2][2] = {};
    #pragma unroll 1
    for (int c = 0; c < 8; ++c) {
        const int k0 = kbase + c * 32;
        const float* bsrc = &B[(k0 + skr) * 512 + nc0 + snc];
        float4 s0 = *(const float4*)(bsrc);
        float4 s1 = *(const float4*)(bsrc + 4);
        float4 s2 = *(const float4*)(bsrc + 8);
        float4 s3 = *(const float4*)(bsrc + 12);
        *(float4*)&bt[kv][skr][snc]      = s0;
        *(float4*)&bt[kv][skr][snc + 4]  = s1;
        *(float4*)&bt[kv][skr][snc + 8]  = s2;
        *(float4*)&bt[kv][skr][snc + 12] = s3;
        float4 a00 = *(const float4*)(px0 + c * 32);
        float4 a01 = *(const float4*)(px0 + c * 32 + 4);
        float4 a10 = *(const float4*)(px1 + c * 32);
        float4 a11 = *(const float4*)(px1 + c * 32 + 4);
        short8 af0, af1;
        af0[0] = (short)f2bf(a00.x); af0[1] = (short)f2bf(a00.y);
        af0[2] = (short)f2bf(a00.z); af0[3] = (short)f2bf(a00.w);
        af0[4] = (short)f2bf(a01.x); af0[5] = (short)f2bf(a01.y);
        af0[6] = (short)f2bf(a01.z); af0[7] = (short)f2bf(a01.w);
        af1[0] = (short)f2bf(a10.x); af1[1] = (short)f2bf(a10.y);
        af1[2] = (short)f2bf(a10.z); af1[3] = (short)f2bf(a10.w);
        af1[4] = (short)f2bf(a11.x); af1[5] = (short)f2bf(a11.y);
        af1[6] = (short)f2bf(a11.z); af1[7] = (short)f2bf(a11.w);
        short8 bf0, bf1;
        #pragma unroll
        for (int q = 0; q < 8; ++q) {
            bf0[q] = (short)f2bf(bt[kv][lk + q][lrow]);
            bf1[q] = (short)f2bf(bt[kv][lk + q][lrow + 16]);
        }
        acc[0][0] = __builtin_amdgcn_mfma_f32_16x16x32_bf16(af0, bf0, acc[0][0], 0, 0, 0);
        acc[0][1] = __builtin_amdgcn_mfma_f32_16x16x32_bf16(af0, bf1, acc[0][1], 0, 0, 0);
        acc[1][0] = __builtin_amdgcn_mfma_f32_16x16x32_bf16(af1, bf0, acc[1][0], 0, 0, 0);
        acc[1][1] = __builtin_amdgcn_mfma_f32_16x16x32_bf16(af1, bf1, acc[1][1], 0, 0, 0);
    }
    if (kv == 1) {
        *(f32x4*)&ps[lane][0]  = acc[0][0];
        *(f32x4*)&ps[lane][4]  = acc[0][1];
        *(f32x4*)&ps[lane][8]  = acc[1][0];
        *(f32x4*)&ps[lane][12] = acc[1][1];
    }
    __syncthreads();
    if (kv == 0) {
        acc[0][0] += *(const f32x4*)&ps[lane][0];
        acc[0][1] += *(const f32x4*)&ps[lane][4];
        acc[1][0] += *(const f32x4*)&ps[lane][8];
        acc[1][1] += *(const f32x4*)&ps[lane][12];
        const int crow = (lane >> 4) * 4, ccol = lane & 15;
        #pragma unroll
        for (int nf = 0; nf < 2; ++nf) {
            int col = n0 + nf * 16 + ccol;
            float cb = catBias[col];
            #pragma unroll
            for (int mf = 0; mf < 2; ++mf) {
                #pragma unroll
                for (int r = 0; r < 4; ++r) {
                    int row = m0 + mf * 16 + crow + r;
                    act[row * NC + col] = f2bf(fast_tanh(acc[mf][nf][r] + cb));
                }
            }
        }
    }
}

// ---------------------------------------------------------------------------
// GEMM2 (fused prep) + exp epilogue -> pw = EA | EM (f32). [FROZEN = r18]
// ---------------------------------------------------------------------------
__global__ __launch_bounds__(128) void k_gemm2(
    const ushort* __restrict__ act, const float* __restrict__ hid2,
    const float* __restrict__ hid2Bias, float* __restrict__ pw)
{
    __shared__ float ps[64][20];
    __shared__ float bt[2][32][33];

    const int t = threadIdx.x;
    const int kv = t >> 6, lane = t & 63;
    const int n0 = blockIdx.x * 32;
    const int m0 = blockIdx.y * 32;
    const bool top = (blockIdx.x < 16);
    const int koff = top ? 0 : 512;
    const int nc0  = top ? n0 : n0 - 512;
    const int lrow = lane & 15, lk = (lane >> 4) * 8;
    const int kbase = kv * 256;

    const int skr = lane >> 1;
    const int snc = (lane & 1) * 16;

    const ushort* pa0 = &act[(m0 + lrow) * NC + koff + kbase + lk];
    const ushort* pa1 = pa0 + 16 * NC;

    f32x4 acc[2][2] = {};
    #pragma unroll 1
    for (int c = 0; c < 8; ++c) {
        const int k0 = kbase + c * 32;
        const float* bsrc = &hid2[(koff + k0 + skr) * 512 + nc0 + snc];
        float4 s0 = *(const float4*)(bsrc);
        float4 s1 = *(const float4*)(bsrc + 4);
        float4 s2 = *(const float4*)(bsrc + 8);
        float4 s3 = *(const float4*)(bsrc + 12);
        *(float4*)&bt[kv][skr][snc]      = s0;
        *(float4*)&bt[kv][skr][snc + 4]  = s1;
        *(float4*)&bt[kv][skr][snc + 8]  = s2;
        *(float4*)&bt[kv][skr][snc + 12] = s3;
        short8 af0 = *(const short8*)(pa0 + c * 32);
        short8 af1 = *(const short8*)(pa1 + c * 32);
        short8 bf0, bf1;
        #pragma unroll
        for (int q = 0; q < 8; ++q) {
            bf0[q] = (short)f2bf(bt[kv][lk + q][lrow]);
            bf1[q] = (short)f2bf(bt[kv][lk + q][lrow + 16]);
        }
        acc[0][0] = __builtin_amdgcn_mfma_f32_16x16x32_bf16(af0, bf0, acc[0][0], 0, 0, 0);
        acc[0][1] = __builtin_amdgcn_mfma_f32_16x16x32_bf16(af0, bf1, acc[0][1], 0, 0, 0);
        acc[1][0] = __builtin_amdgcn_mfma_f32_16x16x32_bf16(af1, bf0, acc[1][0], 0, 0, 0);
        acc[1][1] = __builtin_amdgcn_mfma_f32_16x16x32_bf16(af1, bf1, acc[1][1], 0, 0, 0);
    }
    if (kv == 1) {
        *(f32x4*)&ps[lane][0]  = acc[0][0];
        *(f32x4*)&ps[lane][4]  = acc[0][1];
        *(f32x4*)&ps[lane][8]  = acc[1][0];
        *(f32x4*)&ps[lane][12] = acc[1][1];
    }
    __syncthreads();
    if (kv == 0) {
        acc[0][0] += *(const f32x4*)&ps[lane][0];
        acc[0][1] += *(const f32x4*)&ps[lane][4];
        acc[1][0] += *(const f32x4*)&ps[lane][8];
        acc[1][1] += *(const f32x4*)&ps[lane][12];
        const int crow = (lane >> 4) * 4, ccol = lane & 15;
        #pragma unroll
        for (int nf = 0; nf < 2; ++nf) {
            int col = n0 + nf * 16 + ccol;
            float hb = top ? hid2Bias[col] : 0.0f;
            #pragma unroll
            for (int mf = 0; mf < 2; ++mf) {
                #pragma unroll
                for (int r = 0; r < 4; ++r) {
                    int row = m0 + mf * 16 + crow + r;
                    pw[row * NC + col] = fast_exp2(RLN2_2 * (acc[mf][nf][r] + hb));
                }
            }
        }
    }
}

// ---------------------------------------------------------------------------
// Pairwise: out[i][j] = (outBias + sum w) - 2*sum_h w[h]/(1 + EA[i,h]*EM[j,h])
// NEW: 16i x 32j tile / 4-wave h-split; micro 2i x 4j per lane ->
// LDS reads 7 b128 / 32 evals (was 5 / 16): 3.5 B/eval, LDS pipe ~14 us.
// Batched rcp over 4 j (1 rcp / 4 evals): acc01 += T2*DB, acc23 += T2*DA,
// T2 = {Q.y,Q.x}*R*w, Q = DA*DB. Wave-private staging, no main-loop barriers,
// packed f32x2, w in LDS. Grid 1152 XCD-swz (8|1152) x 4 waves, ~24 waves/CU.
// ---------------------------------------------------------------------------
__global__ __launch_bounds__(256) void k_pair(
    const float* __restrict__ pw, const float* __restrict__ w,
    const float* __restrict__ outBias, float* __restrict__ out)
{
    __shared__ float Ea[4][16][18];
    __shared__ float Em[4][32][18];
    __shared__ float wl[512];

    const int t    = threadIdx.x;
    const int wv   = t >> 6, lane = t & 63;
    const int bid  = blockIdx.x;
    const int sw   = (bid & 7) * 144 + (bid >> 3);   // XCD swizzle (8 | 1152)
    const int it = sw / 24, jt = sw % 24;            // 48 x 24 tiles
    const int i0 = it * 16, j0 = jt * 32;
    const int hb0 = wv * 128;                        // this wave's h-quarter

    // w: each wave stages its own h-quarter; lsum via global + butterfly
    *(float2*)&wl[hb0 + lane * 2] = *(const float2*)&w[hb0 + lane * 2];
    float4 wa = *(const float4*)&w[lane * 8];
    float4 wb = *(const float4*)&w[lane * 8 + 4];
    float lsum = (wa.x + wa.y) + (wa.z + wa.w) + (wb.x + wb.y) + (wb.z + wb.w);
    #pragma unroll
    for (int d = 1; d < 64; d <<= 1) lsum += __shfl_xor(lsum, d, 64);

    // staging geometry: Ea 16 rows x 16 cols (1 f4/lane);
    //                   Em 32 rows x 16 cols (2 f4/lane)
    const int sr  = lane >> 2, sc  = (lane & 3) * 4;
    const int smr = lane >> 1, smc = (lane & 1) * 8;
    const float* srcA = &pw[(i0 + sr)  * NC + hb0 + sc];
    const float* srcM = &pw[(j0 + smr) * NC + 512 + hb0 + smc];

    // compute geometry: li = rows {2li,2li+1}; lj = cols {4lj..4lj+3}
    const int li = lane >> 3, lj = lane & 7;

    float4 fa  = *(const float4*)(srcA);
    float4 fm0 = *(const float4*)(srcM);
    float4 fm1 = *(const float4*)(srcM + 4);

    const f32x2 one2 = {1.0f, 1.0f};
    f32x2 aA01[2] = {}, aA23[2] = {};   // row 2li:   (j0,j1) / (j2,j3)
    f32x2 aB01[2] = {}, aB23[2] = {};   // row 2li+1

    #pragma unroll 1
    for (int c = 0; c < 8; ++c) {        // 8 chunks x 16 h
        const int hh = c * 16;
        *(float4*)&Ea[wv][sr][sc]        = fa;   // wave-private; in-order DS
        *(float4*)&Em[wv][smr][smc]      = fm0;
        *(float4*)&Em[wv][smr][smc + 4]  = fm1;
        if (c < 7) {
            fa  = *(const float4*)(srcA + hh + 16);
            fm0 = *(const float4*)(srcM + hh + 16);
            fm1 = *(const float4*)(srcM + hh + 20);
        }
        #pragma unroll
        for (int hq = 0; hq < 4; ++hq) {
            float4 e0 = *(const float4*)&Ea[wv][2 * li    ][hq * 4];
            float4 e1 = *(const float4*)&Ea[wv][2 * li + 1][hq * 4];
            float4 f0 = *(const float4*)&Em[wv][4 * lj    ][hq * 4];
            float4 f1 = *(const float4*)&Em[wv][4 * lj + 1][hq * 4];
            float4 f2 = *(const float4*)&Em[wv][4 * lj + 2][hq * 4];
            float4 f3 = *(const float4*)&Em[wv][4 * lj + 3][hq * 4];
            float4 w4 = *(const float4*)&wl[hb0 + hh + hq * 4];  // broadcast
            #define ROWQ(EH, WH, A01, A23)                                   \
            {                                                                \
                f32x2 E  = {EH, EH};                                         \
                f32x2 DA = __builtin_elementwise_fma(E, F01, one2);          \
                f32x2 DB = __builtin_elementwise_fma(E, F23, one2);          \
                f32x2 Q  = DA * DB;                                          \
                float R  = fast_rcp(Q.x * Q.y);                              \
                float RW = R * (WH);                                         \
                f32x2 T2 = (f32x2){Q.y, Q.x} * RW;                           \
                A01 = __builtin_elementwise_fma(T2, DB, A01);                \
                A23 = __builtin_elementwise_fma(T2, DA, A23);                \
            }
            #define HSTEP(H, S)                                              \
            {                                                                \
                f32x2 F01 = {f0.H, f1.H};                                    \
                f32x2 F23 = {f2.H, f3.H};                                    \
                ROWQ(e0.H, w4.H, aA01[S], aA23[S])                           \
                ROWQ(e1.H, w4.H, aB01[S], aB23[S])                           \
            }
            HSTEP(x, 0) HSTEP(y, 1) HSTEP(z, 0) HSTEP(w, 1)
            #undef HSTEP
            #undef ROWQ
        }
    }

    f32x2 sA01 = aA01[0] + aA01[1];
    f32x2 sA23 = aA23[0] + aA23[1];
    f32x2 sB01 = aB01[0] + aB01[1];
    f32x2 sB23 = aB23[0] + aB23[1];

    // combine 4 h-quarters: waves 1..3 park 8 partials each in Em overlay
    // (1536 floats <= 2304), wave 0 sums and writes out.
    float* partial = (float*)Em;
    __syncthreads();
    if (wv >= 1) {
        float* p = partial + (wv - 1) * 512 + lane * 8;
        p[0] = sA01.x; p[1] = sA01.y; p[2] = sA23.x; p[3] = sA23.y;
        p[4] = sB01.x; p[5] = sB01.y; p[6] = sB23.x; p[7] = sB23.y;
    }
    __syncthreads();
    if (wv == 0) {
        const float base = lsum + outBias[0];
        float tt[8] = {sA01.x, sA01.y, sA23.x, sA23.y,
                       sB01.x, sB01.y, sB23.x, sB23.y};
        #pragma unroll
        for (int q = 0; q < 3; ++q) {
            const float* p = partial + q * 512 + lane * 8;
            #pragma unroll
            for (int k = 0; k < 8; ++k) tt[k] += p[k];
        }
        const int gi = i0 + 2 * li, gj = j0 + 4 * lj;
        float4 o0, o1;
        o0.x = fmaf(-2.f, tt[0], base);
        o0.y = fmaf(-2.f, tt[1], base);
        o0.z = fmaf(-2.f, tt[2], base);
        o0.w = fmaf(-2.f, tt[3], base);
        o1.x = fmaf(-2.f, tt[4], base);
        o1.y = fmaf(-2.f, tt[5], base);
        o1.z = fmaf(-2.f, tt[6], base);
        o1.w = fmaf(-2.f, tt[7], base);
        *(float4*)&out[gi * TT + gj]       = o0;
        *(float4*)&out[(gi + 1) * TT + gj] = o1;
    }
}

extern "C" void kernel_launch(void* const* d_in, const int* in_sizes, int n_in,
                              void* d_out, int out_size, void* d_ws, size_t ws_size,
                              hipStream_t stream) {
    const float* x        = (const float*)d_in[0];
    const float* foh      = (const float*)d_in[1];
    const float* fom      = (const float*)d_in[2];
    const float* catBias  = (const float*)d_in[3];
    const float* hid2     = (const float*)d_in[4];
    const float* hid2Bias = (const float*)d_in[5];
    const float* outLayer = (const float*)d_in[6];
    const float* outBias  = (const float*)d_in[7];
    float* out = (float*)d_out;

    char* wsb = (char*)d_ws;
    float*  pw  = (float*)(wsb);                        // 768*1024*4
    ushort* act = (ushort*)(wsb + 3145728);             // 768*1024*2

    k_gemm1<<<dim3(32, 24), 128, 0, stream>>>(x, foh, fom, catBias, act);
    k_gemm2<<<dim3(32, 24), 128, 0, stream>>>(act, hid2, hid2Bias, pw);
    k_pair <<<dim3(1152),   256, 0, stream>>>(pw, outLayer, outBias, out);
}

// Round 20
// 55.309 us; speedup vs baseline: 1.0297x; 1.0297x over previous
//
#include <hip/hip_runtime.h>

#define TT 768
#define KD 512
#define NC 1024
#define RLN2_2 2.8853900817779268f   // 2/ln(2)

typedef short short8 __attribute__((ext_vector_type(8)));
typedef float f32x4  __attribute__((ext_vector_type(4)));
typedef float f32x2  __attribute__((ext_vector_type(2)));

__device__ __forceinline__ float fast_exp2(float x) {
#if __has_builtin(__builtin_amdgcn_exp2f)
    return __builtin_amdgcn_exp2f(x);
#else
    return exp2f(x);
#endif
}
__device__ __forceinline__ float fast_rcp(float x) {
#if __has_builtin(__builtin_amdgcn_rcpf)
    return __builtin_amdgcn_rcpf(x);
#else
    return 1.0f / x;
#endif
}
__device__ __forceinline__ float fast_tanh(float x) {
    float e = fast_exp2(x * RLN2_2);
    return fmaf(-2.0f, fast_rcp(e + 1.0f), 1.0f);
}
__device__ __forceinline__ ushort f2bf(float f) {   // RNE f32->bf16
    uint u = __float_as_uint(f);
    u += 0x7fff + ((u >> 16) & 1);
    return (ushort)(u >> 16);
}

// ---------------------------------------------------------------------------
// GEMM1 (fused prep): act = tanh( x @ (foh|fom) + catBias ), bf16 out.
// A fragments: DIRECT from x f32 (k-contiguous) + convert in regs.
// B fragments: per-wave LDS transpose staging ([32][33] pad), cvt in regs.
// 32x32 tile / block, 2-wave K-split, wave-private staging (no in-loop
// barriers). Grid 32x24 = 768 blocks.  [PROVEN r18]
// ---------------------------------------------------------------------------
__global__ __launch_bounds__(128) void k_gemm1(
    const float* __restrict__ x, const float* __restrict__ foh,
    const float* __restrict__ fom, const float* __restrict__ catBias,
    ushort* __restrict__ act)
{
    __shared__ float ps[64][20];
    __shared__ float bt[2][32][33];

    const int t = threadIdx.x;
    const int kv = t >> 6, lane = t & 63;
    const int n0 = blockIdx.x * 32;
    const int m0 = blockIdx.y * 32;
    const float* B = (n0 < 512) ? foh : fom;
    const int nc0  = (n0 < 512) ? n0 : n0 - 512;
    const int lrow = lane & 15, lk = (lane >> 4) * 8;
    const int kbase = kv * 256;

    const int skr = lane >> 1;           // k-row 0..31
    const int snc = (lane & 1) * 16;     // col 0 or 16

    const float* px0 = &x[(m0 + lrow) * KD + kbase + lk];
    const float* px1 = px0 + 16 * KD;

    f32x4 acc[2][2] = {};
    #pragma unroll 1
    for (int c = 0; c < 8; ++c) {
        const int k0 = kbase + c * 32;
        const float* bsrc = &B[(k0 + skr) * 512 + nc0 + snc];
        float4 s0 = *(const float4*)(bsrc);
        float4 s1 = *(const float4*)(bsrc + 4);
        float4 s2 = *(const float4*)(bsrc + 8);
        float4 s3 = *(const float4*)(bsrc + 12);
        *(float4*)&bt[kv][skr][snc]      = s0;
        *(float4*)&bt[kv][skr][snc + 4]  = s1;
        *(float4*)&bt[kv][skr][snc + 8]  = s2;
        *(float4*)&bt[kv][skr][snc + 12] = s3;
        float4 a00 = *(const float4*)(px0 + c * 32);
        float4 a01 = *(const float4*)(px0 + c * 32 + 4);
        float4 a10 = *(const float4*)(px1 + c * 32);
        float4 a11 = *(const float4*)(px1 + c * 32 + 4);
        short8 af0, af1;
        af0[0] = (short)f2bf(a00.x); af0[1] = (short)f2bf(a00.y);
        af0[2] = (short)f2bf(a00.z); af0[3] = (short)f2bf(a00.w);
        af0[4] = (short)f2bf(a01.x); af0[5] = (short)f2bf(a01.y);
        af0[6] = (short)f2bf(a01.z); af0[7] = (short)f2bf(a01.w);
        af1[0] = (short)f2bf(a10.x); af1[1] = (short)f2bf(a10.y);
        af1[2] = (short)f2bf(a10.z); af1[3] = (short)f2bf(a10.w);
        af1[4] = (short)f2bf(a11.x); af1[5] = (short)f2bf(a11.y);
        af1[6] = (short)f2bf(a11.z); af1[7] = (short)f2bf(a11.w);
        short8 bf0, bf1;
        #pragma unroll
        for (int q = 0; q < 8; ++q) {
            bf0[q] = (short)f2bf(bt[kv][lk + q][lrow]);
            bf1[q] = (short)f2bf(bt[kv][lk + q][lrow + 16]);
        }
        acc[0][0] = __builtin_amdgcn_mfma_f32_16x16x32_bf16(af0, bf0, acc[0][0], 0, 0, 0);
        acc[0][1] = __builtin_amdgcn_mfma_f32_16x16x32_bf16(af0, bf1, acc[0][1], 0, 0, 0);
        acc[1][0] = __builtin_amdgcn_mfma_f32_16x16x32_bf16(af1, bf0, acc[1][0], 0, 0, 0);
        acc[1][1] = __builtin_amdgcn_mfma_f32_16x16x32_bf16(af1, bf1, acc[1][1], 0, 0, 0);
    }
    if (kv == 1) {
        *(f32x4*)&ps[lane][0]  = acc[0][0];
        *(f32x4*)&ps[lane][4]  = acc[0][1];
        *(f32x4*)&ps[lane][8]  = acc[1][0];
        *(f32x4*)&ps[lane][12] = acc[1][1];
    }
    __syncthreads();
    if (kv == 0) {
        acc[0][0] += *(const f32x4*)&ps[lane][0];
        acc[0][1] += *(const f32x4*)&ps[lane][4];
        acc[1][0] += *(const f32x4*)&ps[lane][8];
        acc[1][1] += *(const f32x4*)&ps[lane][12];
        const int crow = (lane >> 4) * 4, ccol = lane & 15;
        #pragma unroll
        for (int nf = 0; nf < 2; ++nf) {
            int col = n0 + nf * 16 + ccol;
            float cb = catBias[col];
            #pragma unroll
            for (int mf = 0; mf < 2; ++mf) {
                #pragma unroll
                for (int r = 0; r < 4; ++r) {
                    int row = m0 + mf * 16 + crow + r;
                    act[row * NC + col] = f2bf(fast_tanh(acc[mf][nf][r] + cb));
                }
            }
        }
    }
}

// ---------------------------------------------------------------------------
// GEMM2 (fused prep) + exp epilogue -> pw = EA | EM (f32). [PROVEN r18]
// ---------------------------------------------------------------------------
__global__ __launch_bounds__(128) void k_gemm2(
    const ushort* __restrict__ act, const float* __restrict__ hid2,
    const float* __restrict__ hid2Bias, float* __restrict__ pw)
{
    __shared__ float ps[64][20];
    __shared__ float bt[2][32][33];

    const int t = threadIdx.x;
    const int kv = t >> 6, lane = t & 63;
    const int n0 = blockIdx.x * 32;
    const int m0 = blockIdx.y * 32;
    const bool top = (blockIdx.x < 16);
    const int koff = top ? 0 : 512;
    const int nc0  = top ? n0 : n0 - 512;
    const int lrow = lane & 15, lk = (lane >> 4) * 8;
    const int kbase = kv * 256;

    const int skr = lane >> 1;
    const int snc = (lane & 1) * 16;

    const ushort* pa0 = &act[(m0 + lrow) * NC + koff + kbase + lk];
    const ushort* pa1 = pa0 + 16 * NC;

    f32x4 acc[2][2] = {};
    #pragma unroll 1
    for (int c = 0; c < 8; ++c) {
        const int k0 = kbase + c * 32;
        const float* bsrc = &hid2[(koff + k0 + skr) * 512 + nc0 + snc];
        float4 s0 = *(const float4*)(bsrc);
        float4 s1 = *(const float4*)(bsrc + 4);
        float4 s2 = *(const float4*)(bsrc + 8);
        float4 s3 = *(const float4*)(bsrc + 12);
        *(float4*)&bt[kv][skr][snc]      = s0;
        *(float4*)&bt[kv][skr][snc + 4]  = s1;
        *(float4*)&bt[kv][skr][snc + 8]  = s2;
        *(float4*)&bt[kv][skr][snc + 12] = s3;
        short8 af0 = *(const short8*)(pa0 + c * 32);
        short8 af1 = *(const short8*)(pa1 + c * 32);
        short8 bf0, bf1;
        #pragma unroll
        for (int q = 0; q < 8; ++q) {
            bf0[q] = (short)f2bf(bt[kv][lk + q][lrow]);
            bf1[q] = (short)f2bf(bt[kv][lk + q][lrow + 16]);
        }
        acc[0][0] = __builtin_amdgcn_mfma_f32_16x16x32_bf16(af0, bf0, acc[0][0], 0, 0, 0);
        acc[0][1] = __builtin_amdgcn_mfma_f32_16x16x32_bf16(af0, bf1, acc[0][1], 0, 0, 0);
        acc[1][0] = __builtin_amdgcn_mfma_f32_16x16x32_bf16(af1, bf0, acc[1][0], 0, 0, 0);
        acc[1][1] = __builtin_amdgcn_mfma_f32_16x16x32_bf16(af1, bf1, acc[1][1], 0, 0, 0);
    }
    if (kv == 1) {
        *(f32x4*)&ps[lane][0]  = acc[0][0];
        *(f32x4*)&ps[lane][4]  = acc[0][1];
        *(f32x4*)&ps[lane][8]  = acc[1][0];
        *(f32x4*)&ps[lane][12] = acc[1][1];
    }
    __syncthreads();
    if (kv == 0) {
        acc[0][0] += *(const f32x4*)&ps[lane][0];
        acc[0][1] += *(const f32x4*)&ps[lane][4];
        acc[1][0] += *(const f32x4*)&ps[lane][8];
        acc[1][1] += *(const f32x4*)&ps[lane][12];
        const int crow = (lane >> 4) * 4, ccol = lane & 15;
        #pragma unroll
        for (int nf = 0; nf < 2; ++nf) {
            int col = n0 + nf * 16 + ccol;
            float hb = top ? hid2Bias[col] : 0.0f;
            #pragma unroll
            for (int mf = 0; mf < 2; ++mf) {
                #pragma unroll
                for (int r = 0; r < 4; ++r) {
                    int row = m0 + mf * 16 + crow + r;
                    pw[row * NC + col] = fast_exp2(RLN2_2 * (acc[mf][nf][r] + hb));
                }
            }
        }
    }
}

// ---------------------------------------------------------------------------
// Pairwise [PROVEN r15/r18 best]: 16x16 tile / 4-wave h-split / wave-private
// staging / no main-loop barriers / packed f32x2 math / w in LDS.
// Grid 2304 XCD-swz x 4 waves; VGPR <= 64 -> 32 waves/CU resident.
// ---------------------------------------------------------------------------
__global__ __launch_bounds__(256) void k_pair(
    const float* __restrict__ pw, const float* __restrict__ w,
    const float* __restrict__ outBias, float* __restrict__ out)
{
    __shared__ float Ea[4][16][18];
    __shared__ float Em[4][16][18];
    __shared__ float wl[512];

    const int t    = threadIdx.x;
    const int wv   = t >> 6, lane = t & 63;
    const int bid  = blockIdx.x;
    const int sw   = (bid & 7) * 288 + (bid >> 3);   // XCD swizzle (8 | 2304)
    const int it = sw / 48, jt = sw % 48;
    const int i0 = it * 16, j0 = jt * 16;
    const int hb0 = wv * 128;                        // this wave's h-quarter

    *(float2*)&wl[hb0 + lane * 2] = *(const float2*)&w[hb0 + lane * 2];
    float4 wa = *(const float4*)&w[lane * 8];
    float4 wb = *(const float4*)&w[lane * 8 + 4];
    float lsum = (wa.x + wa.y) + (wa.z + wa.w) + (wb.x + wb.y) + (wb.z + wb.w);
    #pragma unroll
    for (int d = 1; d < 64; d <<= 1) lsum += __shfl_xor(lsum, d, 64);

    const int sr = lane >> 2;            // 0..15
    const int sc = (lane & 3) * 4;       // 0..12
    const float* srcA = &pw[(i0 + sr) * NC + hb0 + sc];
    const float* srcM = &pw[(j0 + sr) * NC + 512 + hb0 + sc];

    const int li = lane >> 3, lj = lane & 7;

    float4 fa = *(const float4*)(srcA);
    float4 fm = *(const float4*)(srcM);

    const f32x2 one2 = {1.0f, 1.0f};
    f32x2 accA[2] = {}, accB[2] = {};

    #pragma unroll 1
    for (int c = 0; c < 8; ++c) {        // 8 chunks x 16 h
        const int hh = c * 16;
        *(float4*)&Ea[wv][sr][sc] = fa;  // wave-private; in-order DS pipe
        *(float4*)&Em[wv][sr][sc] = fm;
        if (c < 7) {
            fa = *(const float4*)(srcA + hh + 16);
            fm = *(const float4*)(srcM + hh + 16);
        }
        #pragma unroll
        for (int hq = 0; hq < 4; ++hq) {
            float4 e0 = *(const float4*)&Ea[wv][2 * li    ][hq * 4];
            float4 e1 = *(const float4*)&Ea[wv][2 * li + 1][hq * 4];
            float4 f0 = *(const float4*)&Em[wv][2 * lj    ][hq * 4];
            float4 f1 = *(const float4*)&Em[wv][2 * lj + 1][hq * 4];
            float4 w4 = *(const float4*)&wl[hb0 + hh + hq * 4];  // broadcast
            #define PKQUAD(DA, DB, WH, ACCA, ACCB)                   \
            {                                                        \
                f32x2 Q  = DA * DB;                                  \
                float pr = Q.x * Q.y;                                \
                float R  = fast_rcp(pr);                             \
                float RW = R * (WH);                                 \
                f32x2 T  = (f32x2){Q.y, Q.x} * RW;                   \
                ACCA = __builtin_elementwise_fma(T, DB, ACCA);       \
                ACCB = __builtin_elementwise_fma(T, DA, ACCB);       \
            }
            #define HSTEP(H, S)                                                     \
            {                                                                       \
                f32x2 F  = {f0.H, f1.H};                                            \
                f32x2 D0 = __builtin_elementwise_fma((f32x2){e0.H, e0.H}, F, one2); \
                f32x2 D1 = __builtin_elementwise_fma((f32x2){e1.H, e1.H}, F, one2); \
                PKQUAD(D0, D1, w4.H, accA[S], accB[S])                              \
            }
            HSTEP(x, 0) HSTEP(y, 1) HSTEP(z, 0) HSTEP(w, 1)
            #undef HSTEP
            #undef PKQUAD
        }
    }

    f32x2 s0 = accA[0] + accA[1];
    f32x2 s1 = accB[0] + accB[1];

    float* partial = (float*)Ea;
    __syncthreads();
    if (wv >= 1) {
        float* p = partial + (wv - 1) * 256 + lane * 4;
        p[0] = s0.x; p[1] = s0.y; p[2] = s1.x; p[3] = s1.y;
    }
    __syncthreads();
    if (wv == 0) {
        const float base = lsum + outBias[0];
        float t00 = s0.x, t01 = s0.y, t10 = s1.x, t11 = s1.y;
        #pragma unroll
        for (int q = 0; q < 3; ++q) {
            const float* p = partial + q * 256 + lane * 4;
            t00 += p[0]; t01 += p[1]; t10 += p[2]; t11 += p[3];
        }
        const int gi = i0 + 2 * li, gj = j0 + 2 * lj;
        float2 o0, o1;
        o0.x = fmaf(-2.f, t00, base);
        o0.y = fmaf(-2.f, t01, base);
        o1.x = fmaf(-2.f, t10, base);
        o1.y = fmaf(-2.f, t11, base);
        *(float2*)&out[gi * TT + gj]       = o0;
        *(float2*)&out[(gi + 1) * TT + gj] = o1;
    }
}

extern "C" void kernel_launch(void* const* d_in, const int* in_sizes, int n_in,
                              void* d_out, int out_size, void* d_ws, size_t ws_size,
                              hipStream_t stream) {
    const float* x        = (const float*)d_in[0];
    const float* foh      = (const float*)d_in[1];
    const float* fom      = (const float*)d_in[2];
    const float* catBias  = (const float*)d_in[3];
    const float* hid2     = (const float*)d_in[4];
    const float* hid2Bias = (const float*)d_in[5];
    const float* outLayer = (const float*)d_in[6];
    const float* outBias  = (const float*)d_in[7];
    float* out = (float*)d_out;

    char* wsb = (char*)d_ws;
    float*  pw  = (float*)(wsb);                        // 768*1024*4
    ushort* act = (ushort*)(wsb + 3145728);             // 768*1024*2

    k_gemm1<<<dim3(32, 24), 128, 0, stream>>>(x, foh, fom, catBias, act);
    k_gemm2<<<dim3(32, 24), 128, 0, stream>>>(act, hid2, hid2Bias, pw);
    k_pair <<<dim3(2304),   256, 0, stream>>>(pw, outLayer, outBias, out);
}